// Round 13
// baseline (214.490 us; speedup 1.0000x reference)
//
#include <hip/hip_runtime.h>

// ---------------------------------------------------------------------------
// SparseGRUBrain: N=70000, H=8, E=1.12M, B=8.
// Pipeline (per call):
//   memset(cnt,cursor) -> hist (rank) -> alloc (block scan + calT transpose)
//   -> edge_pack (SEQUENTIAL 64B bf16 records {Wz,Wr,Wh,cal} in EDGE order +
//      4B eIdx scatter into CSR slots)  -> gru_main.
// gru_main: one wave per neuron; sparse loop: eIdx (prefetched one iteration
// ahead) -> ONE random 64B self-contained record read -> 24 FMAs. Dense tail
// via xor reduce-scatter.
// Key evidence trail: R11 (payload scatter 87us + depth-1 gru 85us) vs
// R12 (index scatter + depth-2 3-stream gru 139us). This round: index scatter
// + depth-2 SINGLE-stream pipelined gru.
// Workspace (bytes):
//   [0,      280K)   cnt
//   [448K,   +4)     cursor
//   [512K,   +560K)  rowCnt (int2 per neuron: {begin, count})
//   [1280K,  +4.5M)  rank
//   [6M,     +2.24M) calT (N x 8 f32)
//   [9M,     +4.5M)  eIdxCSR
//   [14M,    +72M)   recs (E x 64B records, EDGE order)
// ---------------------------------------------------------------------------

__device__ __forceinline__ float fast_sigmoid(float x) {
    return 1.0f / (1.0f + __expf(-x));
}
__device__ __forceinline__ float fast_tanh(float x) {
    return 2.0f / (1.0f + __expf(-2.0f * x)) - 1.0f;
}

// fp32 -> bf16 bits, round-to-nearest-even
__device__ __forceinline__ unsigned bfr(float x) {
    unsigned u = __float_as_uint(x);
    return (u + 0x7fffu + ((u >> 16) & 1u)) >> 16;
}
__device__ __forceinline__ uint4 pack8(float4 a, float4 b) {
    uint4 r;
    r.x = bfr(a.x) | (bfr(a.y) << 16);
    r.y = bfr(a.z) | (bfr(a.w) << 16);
    r.z = bfr(b.x) | (bfr(b.y) << 16);
    r.w = bfr(b.z) | (bfr(b.w) << 16);
    return r;
}

// unpack 8 bf16 from uint4, fma into acc[8] with scalar c
#define BFMA(acc, p, c)                                                        \
    {                                                                          \
        acc[0] += __uint_as_float((p).x << 16) * (c);                          \
        acc[1] += __uint_as_float((p).x & 0xffff0000u) * (c);                  \
        acc[2] += __uint_as_float((p).y << 16) * (c);                          \
        acc[3] += __uint_as_float((p).y & 0xffff0000u) * (c);                  \
        acc[4] += __uint_as_float((p).z << 16) * (c);                          \
        acc[5] += __uint_as_float((p).z & 0xffff0000u) * (c);                  \
        acc[6] += __uint_as_float((p).w << 16) * (c);                          \
        acc[7] += __uint_as_float((p).w & 0xffff0000u) * (c);                  \
    }

// cnt[t]++ per edge; atomic return = this edge's rank within its tgt bucket.
__global__ void hist_kernel(const int* __restrict__ tgt, int* __restrict__ cnt,
                            int* __restrict__ rank, int E) {
    int i = blockIdx.x * blockDim.x + threadIdx.x;
    int base = i * 4;
    if (base + 3 < E) {
        int4 t = *(const int4*)(tgt + base);
        int4 r;
        r.x = atomicAdd(&cnt[t.x], 1);
        r.y = atomicAdd(&cnt[t.y], 1);
        r.z = atomicAdd(&cnt[t.z], 1);
        r.w = atomicAdd(&cnt[t.w], 1);
        *(int4*)(rank + base) = r;
    } else {
        for (int k = base; k < E; ++k) rank[k] = atomicAdd(&cnt[tgt[k]], 1);
    }
}

// Row allocation (block scan + one global atomic per block) fused with the
// calcium transpose. rowCnt = {begin, count}; calT[n][b] = cal[b][n].
__global__ __launch_bounds__(256) void alloc_kernel(const int* __restrict__ cnt,
                                                    int2* __restrict__ rowCnt,
                                                    int* __restrict__ cursor,
                                                    const float* __restrict__ cal,
                                                    float* __restrict__ calT, int N) {
    __shared__ int waveSum[4];
    const int n = blockIdx.x * 256 + threadIdx.x;
    const int lane = threadIdx.x & 63;
    const int wid = threadIdx.x >> 6;
    int c = (n < N) ? cnt[n] : 0;
    int pre = c;
#pragma unroll
    for (int off = 1; off < 64; off <<= 1) {
        int v = __shfl_up(pre, off, 64);
        if (lane >= off) pre += v;
    }
    if (lane == 63) waveSum[wid] = pre;
    __syncthreads();
    if (threadIdx.x == 0) {
        int s0 = waveSum[0], s1 = waveSum[1], s2 = waveSum[2], s3 = waveSum[3];
        int base = atomicAdd(cursor, s0 + s1 + s2 + s3);
        waveSum[0] = base;
        waveSum[1] = base + s0;
        waveSum[2] = base + s0 + s1;
        waveSum[3] = base + s0 + s1 + s2;
    }
    __syncthreads();
    if (n < N) {
        rowCnt[n] = make_int2(waveSum[wid] + (pre - c), c);
        float v[8];
#pragma unroll
        for (int b = 0; b < 8; ++b) v[b] = cal[(size_t)b * N + n];
        float4* o = (float4*)(calT + (size_t)n * 8);
        o[0] = make_float4(v[0], v[1], v[2], v[3]);
        o[1] = make_float4(v[4], v[5], v[6], v[7]);
    }
}

// Per edge i: build the self-contained 64B bf16 record {Wz,Wr,Wh,cal[src]} at
// recs[i] (SEQUENTIAL write) and scatter only the 4B index into its CSR slot.
__global__ __launch_bounds__(256) void edge_pack(
    const int* __restrict__ src, const int* __restrict__ tgt,
    const int* __restrict__ rank, const int2* __restrict__ rowCnt,
    const float* __restrict__ Wz, const float* __restrict__ Wr,
    const float* __restrict__ Wh, const float* __restrict__ calT,
    uint4* __restrict__ recs, int* __restrict__ eIdxCSR, int E) {
    int i = blockIdx.x * 256 + threadIdx.x;
    if (i >= E) return;
    int t = tgt[i];
    eIdxCSR[rowCnt[t].x + rank[i]] = i;   // only scattered write (4B)
    const float4* wz4 = (const float4*)(Wz + (size_t)i * 8);
    const float4* wr4 = (const float4*)(Wr + (size_t)i * 8);
    const float4* wh4 = (const float4*)(Wh + (size_t)i * 8);
    const float4* ca4 = (const float4*)(calT + (size_t)src[i] * 8);
    uint4* rp = recs + (size_t)i * 4;
    rp[0] = pack8(wz4[0], wz4[1]);
    rp[1] = pack8(wr4[0], wr4[1]);
    rp[2] = pack8(wh4[0], wh4[1]);
    rp[3] = pack8(ca4[0], ca4[1]);
}

// xor reduce-scatter over the 8 s-lanes: input v[0..7] partials per lane,
// output = fully-reduced value for element index s (lane bits 3,4,5).
__device__ __forceinline__ float rscatter(float v[8], int lane) {
    const bool s0 = (lane & 8) != 0;
    const bool s1 = (lane & 16) != 0;
    const bool s2 = (lane & 32) != 0;
    float w0, w1, w2, w3, x0, x1;
    { float k = s0 ? v[1] : v[0], g = s0 ? v[0] : v[1]; w0 = k + __shfl_xor(g, 8, 64); }
    { float k = s0 ? v[3] : v[2], g = s0 ? v[2] : v[3]; w1 = k + __shfl_xor(g, 8, 64); }
    { float k = s0 ? v[5] : v[4], g = s0 ? v[4] : v[5]; w2 = k + __shfl_xor(g, 8, 64); }
    { float k = s0 ? v[7] : v[6], g = s0 ? v[6] : v[7]; w3 = k + __shfl_xor(g, 8, 64); }
    { float k = s1 ? w1 : w0, g = s1 ? w0 : w1; x0 = k + __shfl_xor(g, 16, 64); }
    { float k = s1 ? w3 : w2, g = s1 ? w2 : w3; x1 = k + __shfl_xor(g, 16, 64); }
    float k = s2 ? x1 : x0, g = s2 ? x0 : x1;
    return k + __shfl_xor(g, 32, 64);
}

// Main: one wave per neuron, 256-thread blocks (4 neurons). lane = s*8 + b.
// Sparse loop: eIdx prefetched one iteration ahead; record read is a single
// random 64B line, fully consumed (weights + this lane's bf16 calcium).
__global__ __launch_bounds__(256) void gru_main(
    const float* __restrict__ hidden, const uint4* __restrict__ recs,
    const int* __restrict__ eIdxCSR,
    const float* __restrict__ Uz, const float* __restrict__ Ur,
    const float* __restrict__ Uh, const float* __restrict__ bz,
    const float* __restrict__ br, const float* __restrict__ bh,
    const float* __restrict__ proj, const int2* __restrict__ rowCnt,
    float* __restrict__ outCal, float* __restrict__ outHid, int N) {
    const int lane = threadIdx.x & 63;
    const int n = blockIdx.x * 4 + (threadIdx.x >> 6);
    if (n >= N) return;
    const int s = lane >> 3;  // slot / h-element index
    const int b = lane & 7;   // batch

    const int2 rc = rowCnt[n];
    const int start = rc.x;
    const int end = rc.x + rc.y;

    // ---- hoisted dense-phase loads (latency hides under the sparse loop) ----
    const float hvS = hidden[((b * N + n) << 3) + s];
    const int ub = (n << 6) + (s << 3);
    float4 uz0 = *(const float4*)(Uz + ub);
    float4 uz1 = *(const float4*)(Uz + ub + 4);
    float4 ur0 = *(const float4*)(Ur + ub);
    float4 ur1 = *(const float4*)(Ur + ub + 4);
    float4 uh0 = *(const float4*)(Uh + ub);
    float4 uh1 = *(const float4*)(Uh + ub + 4);
    const float bzS = bz[(n << 3) + s];
    const float brS = br[(n << 3) + s];
    const float bhS = bh[(n << 3) + s];
    const float pjS = proj[s];

    float az[8] = {0, 0, 0, 0, 0, 0, 0, 0};
    float ar[8] = {0, 0, 0, 0, 0, 0, 0, 0};
    float ah[8] = {0, 0, 0, 0, 0, 0, 0, 0};

    // ---- sparse phase: lane s handles CSR slots j = start+s, +8, ...
    // eIdx is software-pipelined one iteration ahead of the record read.
    const unsigned short* recsH = (const unsigned short*)recs;
    int j = start + s;
    int e = (j < end) ? eIdxCSR[j] : 0;
    while (j < end) {
        int jn = j + 8;
        int en = (jn < end) ? eIdxCSR[jn] : 0;  // prefetch next index
        const uint4* rp = recs + (size_t)e * 4;
        uint4 pz = rp[0];
        uint4 pr = rp[1];
        uint4 ph = rp[2];
        unsigned cb = recsH[((size_t)e << 5) + 24 + b];
        float c = __uint_as_float(cb << 16);
        BFMA(az, pz, c);
        BFMA(ar, pr, c);
        BFMA(ah, ph, c);
        j = jn;
        e = en;
    }

    // ---- slot-parallel recurrent partials for h = s ----
    az[0] += hvS * uz0.x; az[1] += hvS * uz0.y; az[2] += hvS * uz0.z; az[3] += hvS * uz0.w;
    az[4] += hvS * uz1.x; az[5] += hvS * uz1.y; az[6] += hvS * uz1.z; az[7] += hvS * uz1.w;
    ar[0] += hvS * ur0.x; ar[1] += hvS * ur0.y; ar[2] += hvS * ur0.z; ar[3] += hvS * ur0.w;
    ar[4] += hvS * ur1.x; ar[5] += hvS * ur1.y; ar[6] += hvS * ur1.z; ar[7] += hvS * ur1.w;

    // ---- reduce-scatter -> element-s scalars ----
    float AZ = rscatter(az, lane);
    float AR = rscatter(ar, lane);
    float z = fast_sigmoid(AZ + bzS);
    float r = fast_sigmoid(AR + brS);
    float rhS = r * hvS;

    ah[0] += rhS * uh0.x; ah[1] += rhS * uh0.y; ah[2] += rhS * uh0.z; ah[3] += rhS * uh0.w;
    ah[4] += rhS * uh1.x; ah[5] += rhS * uh1.y; ah[6] += rhS * uh1.z; ah[7] += rhS * uh1.w;
    float AH = rscatter(ah, lane);
    float ht = fast_tanh(AH + bhS);
    float hn = (1.0f - z) * hvS + z * ht;

    // ---- projection: butterfly all-reduce over s ----
    float cv = hn * pjS;
    cv += __shfl_xor(cv, 8, 64);
    cv += __shfl_xor(cv, 16, 64);
    cv += __shfl_xor(cv, 32, 64);

    outHid[((b * N + n) << 3) + s] = hn;
    if (s == 0) outCal[b * N + n] = fmaxf(cv, 0.0f);
}

extern "C" void kernel_launch(void* const* d_in, const int* in_sizes, int n_in,
                              void* d_out, int out_size, void* d_ws, size_t ws_size,
                              hipStream_t stream) {
    const float* calcium = (const float*)d_in[0];
    const float* hidden  = (const float*)d_in[1];
    const int*   src     = (const int*)d_in[2];
    const int*   tgt     = (const int*)d_in[3];
    const float* Wz      = (const float*)d_in[4];
    const float* Wr      = (const float*)d_in[5];
    const float* Wh      = (const float*)d_in[6];
    const float* Uz      = (const float*)d_in[7];
    const float* Ur      = (const float*)d_in[8];
    const float* Uh      = (const float*)d_in[9];
    const float* bz      = (const float*)d_in[10];
    const float* br      = (const float*)d_in[11];
    const float* bh      = (const float*)d_in[12];
    const float* proj    = (const float*)d_in[13];

    const int E = in_sizes[2];
    const int H = in_sizes[13];           // 8
    const int N = in_sizes[10] / H;       // 70000
    (void)n_in; (void)out_size; (void)ws_size;

    float* out = (float*)d_out;
    float* outCal = out;
    float* outHid = out + (size_t)in_sizes[0];

    char* ws = (char*)d_ws;
    int*   cnt     = (int*)ws;
    int*   cursor  = (int*)(ws + (448 << 10));
    int2*  rowCnt  = (int2*)(ws + (512 << 10));
    int*   rank    = (int*)(ws + (1280 << 10));
    float* calT    = (float*)(ws + (6 << 20));
    int*   eIdxCSR = (int*)(ws + (9 << 20));
    uint4* recs    = (uint4*)(ws + (14 << 20));

    // zero cnt [0,280K) and cursor (at 448K) in one memset
    hipMemsetAsync(ws, 0, (448 << 10) + 4, stream);

    hist_kernel<<<((E + 3) / 4 + 255) / 256, 256, 0, stream>>>(tgt, cnt, rank, E);
    alloc_kernel<<<(N + 255) / 256, 256, 0, stream>>>(
        cnt, rowCnt, cursor, calcium, calT, N);
    edge_pack<<<(E + 255) / 256, 256, 0, stream>>>(
        src, tgt, rank, rowCnt, Wz, Wr, Wh, calT, recs, eIdxCSR, E);
    gru_main<<<(N + 3) / 4, 256, 0, stream>>>(
        hidden, recs, eIdxCSR, Uz, Ur, Uh, bz, br, bh, proj,
        rowCnt, outCal, outHid, N);
}

// Round 14
// 194.297 us; speedup vs baseline: 1.1039x; 1.1039x over previous
//
#include <hip/hip_runtime.h>

// ---------------------------------------------------------------------------
// SparseGRUBrain: N=70000, H=8, E=1.12M, B=8.
// Pipeline (per call): memset(cnt,cursor) -> hist(+calT transpose, rank) ->
//   alloc (block scan + one global atomic per block) -> scatter_conv (streams
//   W fp32 -> 64B bf16 records {Wz,Wr,Wh,cal[8]bf16}) -> gru_main.
// R14 change: gru_main arithmetic on float2 ext-vectors so the backend emits
// v_pk_fma_f32 (2 FMAs/instr) -- tests the "VALU/issue-bound" theory.
// Per-element accumulation order is IDENTICAL to R11 (absmax control 0.03125).
// Workspace (bytes):
//   [0,      280K)   cnt
//   [448K,   +4)     cursor
//   [512K,   +560K)  rowCnt (int2 per neuron: {begin, count})
//   [1280K,  +4.5M)  rank
//   [5888K,  +2.3M)  calT ((N+1) x 8 f32)
//   [8320K,  +72M)   recs (E x 64B records)
// ---------------------------------------------------------------------------

typedef float f2 __attribute__((ext_vector_type(2)));

__device__ __forceinline__ float fast_sigmoid(float x) {
    return 1.0f / (1.0f + __expf(-x));
}
__device__ __forceinline__ float fast_tanh(float x) {
    return 2.0f / (1.0f + __expf(-2.0f * x)) - 1.0f;
}

// fp32 -> bf16 bits, round-to-nearest-even
__device__ __forceinline__ unsigned bfr(float x) {
    unsigned u = __float_as_uint(x);
    return (u + 0x7fffu + ((u >> 16) & 1u)) >> 16;
}
__device__ __forceinline__ uint4 pack8(float4 a, float4 b) {
    uint4 r;
    r.x = bfr(a.x) | (bfr(a.y) << 16);
    r.y = bfr(a.z) | (bfr(a.w) << 16);
    r.z = bfr(b.x) | (bfr(b.y) << 16);
    r.w = bfr(b.z) | (bfr(b.w) << 16);
    return r;
}

// unpack 8 bf16 from uint4 into 4 float2 pairs, packed-fma with splatted c2
#define BFMA2(acc, p, c2)                                                      \
    {                                                                          \
        f2 w;                                                                  \
        w.x = __uint_as_float((p).x << 16);                                    \
        w.y = __uint_as_float((p).x & 0xffff0000u);                            \
        acc[0] = __builtin_elementwise_fma(w, c2, acc[0]);                     \
        w.x = __uint_as_float((p).y << 16);                                    \
        w.y = __uint_as_float((p).y & 0xffff0000u);                            \
        acc[1] = __builtin_elementwise_fma(w, c2, acc[1]);                     \
        w.x = __uint_as_float((p).z << 16);                                    \
        w.y = __uint_as_float((p).z & 0xffff0000u);                            \
        acc[2] = __builtin_elementwise_fma(w, c2, acc[2]);                     \
        w.x = __uint_as_float((p).w << 16);                                    \
        w.y = __uint_as_float((p).w & 0xffff0000u);                            \
        acc[3] = __builtin_elementwise_fma(w, c2, acc[3]);                     \
    }

// cnt[t]++ per edge (atomic return = rank within bucket); threads <= N also
// build calT (transpose of calcium, row N zeroed).
__global__ void hist_kernel(const int* __restrict__ tgt, int* __restrict__ cnt,
                            int* __restrict__ rank, const float* __restrict__ cal,
                            float* __restrict__ calT, int N, int E) {
    int i = blockIdx.x * blockDim.x + threadIdx.x;
    if (i <= N) {
        float4* o = (float4*)(calT + (size_t)i * 8);
        if (i == N) {
            o[0] = make_float4(0.f, 0.f, 0.f, 0.f);
            o[1] = make_float4(0.f, 0.f, 0.f, 0.f);
        } else {
            float v[8];
#pragma unroll
            for (int b = 0; b < 8; ++b) v[b] = cal[(size_t)b * N + i];
            o[0] = make_float4(v[0], v[1], v[2], v[3]);
            o[1] = make_float4(v[4], v[5], v[6], v[7]);
        }
    }
    int base = i * 4;
    if (base + 3 < E) {
        int4 t = *(const int4*)(tgt + base);
        int4 r;
        r.x = atomicAdd(&cnt[t.x], 1);
        r.y = atomicAdd(&cnt[t.y], 1);
        r.z = atomicAdd(&cnt[t.z], 1);
        r.w = atomicAdd(&cnt[t.w], 1);
        *(int4*)(rank + base) = r;
    } else {
        for (int k = base; k < E; ++k) rank[k] = atomicAdd(&cnt[tgt[k]], 1);
    }
}

// Row allocation without a global scan: block-local exclusive scan of cnt,
// one atomicAdd(cursor, blockTotal) per block. Writes rowCnt = {begin, count}.
__global__ __launch_bounds__(256) void alloc_kernel(const int* __restrict__ cnt,
                                                    int2* __restrict__ rowCnt,
                                                    int* __restrict__ cursor, int N) {
    __shared__ int waveSum[4];
    const int n = blockIdx.x * 256 + threadIdx.x;
    const int lane = threadIdx.x & 63;
    const int wid = threadIdx.x >> 6;
    int c = (n < N) ? cnt[n] : 0;
    int pre = c;
#pragma unroll
    for (int off = 1; off < 64; off <<= 1) {
        int v = __shfl_up(pre, off, 64);
        if (lane >= off) pre += v;
    }
    if (lane == 63) waveSum[wid] = pre;
    __syncthreads();
    if (threadIdx.x == 0) {
        int s0 = waveSum[0], s1 = waveSum[1], s2 = waveSum[2], s3 = waveSum[3];
        int base = atomicAdd(cursor, s0 + s1 + s2 + s3);
        waveSum[0] = base;
        waveSum[1] = base + s0;
        waveSum[2] = base + s0 + s1;
        waveSum[3] = base + s0 + s1 + s2;
    }
    __syncthreads();
    if (n < N) rowCnt[n] = make_int2(waveSum[wid] + (pre - c), c);
}

// Streams W (coalesced), converts to bf16; gathers calT[src] and packs the 8
// batch values as bf16 into the record's 4th 16B word. Record = one 64B line:
// {Wz 8xbf16, Wr 8xbf16, Wh 8xbf16, cal 8xbf16}. 2 edges/thread for ILP.
__global__ __launch_bounds__(256) void scatter_conv(
    const int* __restrict__ src, const int* __restrict__ tgt,
    const int* __restrict__ rank, const int2* __restrict__ rowCnt,
    const float* __restrict__ Wz, const float* __restrict__ Wr,
    const float* __restrict__ Wh, const float* __restrict__ calT,
    uint4* __restrict__ recs, int E) {
    int i0 = (blockIdx.x * 256 + threadIdx.x) * 2;
    if (i0 + 1 < E) {
        int2 t2 = *(const int2*)(tgt + i0);
        int2 r2 = *(const int2*)(rank + i0);
        int2 s2 = *(const int2*)(src + i0);
        int posA = rowCnt[t2.x].x + r2.x;
        int posB = rowCnt[t2.y].x + r2.y;
        const float4* caA = (const float4*)(calT + (size_t)s2.x * 8);
        const float4* caB = (const float4*)(calT + (size_t)s2.y * 8);
        const float4* wzA = (const float4*)(Wz + (size_t)i0 * 8);
        const float4* wrA = (const float4*)(Wr + (size_t)i0 * 8);
        const float4* whA = (const float4*)(Wh + (size_t)i0 * 8);
        uint4* rpA = recs + (size_t)posA * 4;
        uint4* rpB = recs + (size_t)posB * 4;
        rpA[0] = pack8(wzA[0], wzA[1]);
        rpA[1] = pack8(wrA[0], wrA[1]);
        rpA[2] = pack8(whA[0], whA[1]);
        rpA[3] = pack8(caA[0], caA[1]);
        rpB[0] = pack8(wzA[2], wzA[3]);
        rpB[1] = pack8(wrA[2], wrA[3]);
        rpB[2] = pack8(whA[2], whA[3]);
        rpB[3] = pack8(caB[0], caB[1]);
    } else {
        for (int i = i0; i < E; ++i) {
            int pos = rowCnt[tgt[i]].x + rank[i];
            const float4* ca4 = (const float4*)(calT + (size_t)src[i] * 8);
            const float4* wz4 = (const float4*)(Wz + (size_t)i * 8);
            const float4* wr4 = (const float4*)(Wr + (size_t)i * 8);
            const float4* wh4 = (const float4*)(Wh + (size_t)i * 8);
            uint4* rp = recs + (size_t)pos * 4;
            rp[0] = pack8(wz4[0], wz4[1]);
            rp[1] = pack8(wr4[0], wr4[1]);
            rp[2] = pack8(wh4[0], wh4[1]);
            rp[3] = pack8(ca4[0], ca4[1]);
        }
    }
}

// xor reduce-scatter over the 8 s-lanes: input v[0..7] partials per lane,
// output = fully-reduced value for element index s (lane bits 3,4,5).
__device__ __forceinline__ float rscatter(float v[8], int lane) {
    const bool s0 = (lane & 8) != 0;
    const bool s1 = (lane & 16) != 0;
    const bool s2 = (lane & 32) != 0;
    float w0, w1, w2, w3, x0, x1;
    { float k = s0 ? v[1] : v[0], g = s0 ? v[0] : v[1]; w0 = k + __shfl_xor(g, 8, 64); }
    { float k = s0 ? v[3] : v[2], g = s0 ? v[2] : v[3]; w1 = k + __shfl_xor(g, 8, 64); }
    { float k = s0 ? v[5] : v[4], g = s0 ? v[4] : v[5]; w2 = k + __shfl_xor(g, 8, 64); }
    { float k = s0 ? v[7] : v[6], g = s0 ? v[6] : v[7]; w3 = k + __shfl_xor(g, 8, 64); }
    { float k = s1 ? w1 : w0, g = s1 ? w0 : w1; x0 = k + __shfl_xor(g, 16, 64); }
    { float k = s1 ? w3 : w2, g = s1 ? w2 : w3; x1 = k + __shfl_xor(g, 16, 64); }
    float k = s2 ? x1 : x0, g = s2 ? x0 : x1;
    return k + __shfl_xor(g, 32, 64);
}

// Main: one wave per neuron, 256-thread blocks (4 neurons). lane = s*8 + b.
// Sparse loop streams self-contained 64B records; all math packed f32x2.
__global__ __launch_bounds__(256) void gru_main(
    const float* __restrict__ hidden, const uint4* __restrict__ recs,
    const float* __restrict__ Uz, const float* __restrict__ Ur,
    const float* __restrict__ Uh, const float* __restrict__ bz,
    const float* __restrict__ br, const float* __restrict__ bh,
    const float* __restrict__ proj, const int2* __restrict__ rowCnt,
    float* __restrict__ outCal, float* __restrict__ outHid, int N) {
    const int lane = threadIdx.x & 63;
    const int n = blockIdx.x * 4 + (threadIdx.x >> 6);
    if (n >= N) return;
    const int s = lane >> 3;  // slot / h-element index
    const int b = lane & 7;   // batch

    const int2 rc = rowCnt[n];
    const int start = rc.x;
    const int end = rc.x + rc.y;

    // ---- hoisted dense-phase loads (latency hides under the sparse loop) ----
    const float hvS = hidden[((b * N + n) << 3) + s];
    const int ub = (n << 6) + (s << 3);
    const f2* uz2 = (const f2*)(Uz + ub);
    const f2* ur2 = (const f2*)(Ur + ub);
    const f2* uh2 = (const f2*)(Uh + ub);
    f2 uzr[4], urr[4], uhr[4];
#pragma unroll
    for (int k = 0; k < 4; ++k) {
        uzr[k] = uz2[k];
        urr[k] = ur2[k];
        uhr[k] = uh2[k];
    }
    const float bzS = bz[(n << 3) + s];
    const float brS = br[(n << 3) + s];
    const float bhS = bh[(n << 3) + s];
    const float pjS = proj[s];

    f2 az2[4], ar2[4], ah2[4];
#pragma unroll
    for (int k = 0; k < 4; ++k) {
        az2[k] = (f2){0.0f, 0.0f};
        ar2[k] = (f2){0.0f, 0.0f};
        ah2[k] = (f2){0.0f, 0.0f};
    }

    // ---- sparse phase: lane s streams records j = start+s, +8, ... ----
    const unsigned short* recsH = (const unsigned short*)recs;
    for (int j = start + s; j < end; j += 8) {
        const uint4* rp = recs + (size_t)j * 4;
        uint4 pz = rp[0];
        uint4 pr = rp[1];
        uint4 ph = rp[2];
        unsigned cb = recsH[((size_t)j << 5) + 24 + b];
        float c = __uint_as_float(cb << 16);
        f2 c2 = {c, c};
        BFMA2(az2, pz, c2);
        BFMA2(ar2, pr, c2);
        BFMA2(ah2, ph, c2);
    }

    // ---- slot-parallel recurrent partials for h = s (packed) ----
    f2 hv2 = {hvS, hvS};
#pragma unroll
    for (int k = 0; k < 4; ++k) {
        az2[k] = __builtin_elementwise_fma(uzr[k], hv2, az2[k]);
        ar2[k] = __builtin_elementwise_fma(urr[k], hv2, ar2[k]);
    }

    // ---- reduce-scatter -> element-s scalars ----
    float az[8], ar[8];
#pragma unroll
    for (int k = 0; k < 4; ++k) {
        az[2 * k] = az2[k].x; az[2 * k + 1] = az2[k].y;
        ar[2 * k] = ar2[k].x; ar[2 * k + 1] = ar2[k].y;
    }
    float AZ = rscatter(az, lane);
    float AR = rscatter(ar, lane);
    float z = fast_sigmoid(AZ + bzS);
    float r = fast_sigmoid(AR + brS);
    float rhS = r * hvS;

    f2 rh2 = {rhS, rhS};
#pragma unroll
    for (int k = 0; k < 4; ++k) {
        ah2[k] = __builtin_elementwise_fma(uhr[k], rh2, ah2[k]);
    }
    float ah[8];
#pragma unroll
    for (int k = 0; k < 4; ++k) {
        ah[2 * k] = ah2[k].x; ah[2 * k + 1] = ah2[k].y;
    }
    float AH = rscatter(ah, lane);
    float ht = fast_tanh(AH + bhS);
    float hn = (1.0f - z) * hvS + z * ht;

    // ---- projection: butterfly all-reduce over s ----
    float cv = hn * pjS;
    cv += __shfl_xor(cv, 8, 64);
    cv += __shfl_xor(cv, 16, 64);
    cv += __shfl_xor(cv, 32, 64);

    outHid[((b * N + n) << 3) + s] = hn;
    if (s == 0) outCal[b * N + n] = fmaxf(cv, 0.0f);
}

extern "C" void kernel_launch(void* const* d_in, const int* in_sizes, int n_in,
                              void* d_out, int out_size, void* d_ws, size_t ws_size,
                              hipStream_t stream) {
    const float* calcium = (const float*)d_in[0];
    const float* hidden  = (const float*)d_in[1];
    const int*   src     = (const int*)d_in[2];
    const int*   tgt     = (const int*)d_in[3];
    const float* Wz      = (const float*)d_in[4];
    const float* Wr      = (const float*)d_in[5];
    const float* Wh      = (const float*)d_in[6];
    const float* Uz      = (const float*)d_in[7];
    const float* Ur      = (const float*)d_in[8];
    const float* Uh      = (const float*)d_in[9];
    const float* bz      = (const float*)d_in[10];
    const float* br      = (const float*)d_in[11];
    const float* bh      = (const float*)d_in[12];
    const float* proj    = (const float*)d_in[13];

    const int E = in_sizes[2];
    const int H = in_sizes[13];           // 8
    const int N = in_sizes[10] / H;       // 70000
    (void)n_in; (void)out_size; (void)ws_size;

    float* out = (float*)d_out;
    float* outCal = out;
    float* outHid = out + (size_t)in_sizes[0];

    char* ws = (char*)d_ws;
    int*   cnt    = (int*)ws;
    int*   cursor = (int*)(ws + (448 << 10));
    int2*  rowCnt = (int2*)(ws + (512 << 10));
    int*   rank   = (int*)(ws + (1280 << 10));
    float* calT   = (float*)(ws + (5888 << 10));
    uint4* recs   = (uint4*)(ws + (8320 << 10));

    // zero cnt [0,280K) and cursor (at 448K) in one memset
    hipMemsetAsync(ws, 0, (448 << 10) + 4, stream);

    int histThreads = (E + 3) / 4;  // 280000 >= N+1, covers calT duty too
    hist_kernel<<<(histThreads + 255) / 256, 256, 0, stream>>>(
        tgt, cnt, rank, calcium, calT, N, E);
    alloc_kernel<<<(N + 255) / 256, 256, 0, stream>>>(cnt, rowCnt, cursor, N);
    scatter_conv<<<((E + 1) / 2 + 255) / 256, 256, 0, stream>>>(
        src, tgt, rank, rowCnt, Wz, Wr, Wh, calT, recs, E);
    gru_main<<<(N + 3) / 4, 256, 0, stream>>>(
        hidden, recs, Uz, Ur, Uh, bz, br, bh, proj,
        rowCnt, outCal, outHid, N);
}

// Round 15
// 180.663 us; speedup vs baseline: 1.1872x; 1.0755x over previous
//
#include <hip/hip_runtime.h>

// ---------------------------------------------------------------------------
// SparseGRUBrain: N=70000, H=8, E=1.12M, B=8.
// Pipeline (per call): memset(cnt,cursor) -> hist(+calT transpose, rank) ->
//   alloc (block scan + one global atomic per block) -> pack_store (LANE-
//   COOPERATIVE: 4 lanes per edge, each packs+stores one 16B quarter of the
//   64B record {Wz,Wr,Wh,cal} -> every record is ONE full-line coalesced
//   store) -> gru_main (R14 form: packed f32x2 math, streaming records).
// Workspace (bytes):
//   [0,      280K)   cnt
//   [448K,   +4)     cursor
//   [512K,   +560K)  rowCnt (int2 per neuron: {begin, count})
//   [1280K,  +4.5M)  rank
//   [5888K,  +2.3M)  calT ((N+1) x 8 f32)
//   [8320K,  +72M)   recs (E x 64B records)
// ---------------------------------------------------------------------------

typedef float f2 __attribute__((ext_vector_type(2)));

__device__ __forceinline__ float fast_sigmoid(float x) {
    return 1.0f / (1.0f + __expf(-x));
}
__device__ __forceinline__ float fast_tanh(float x) {
    return 2.0f / (1.0f + __expf(-2.0f * x)) - 1.0f;
}

// fp32 -> bf16 bits, round-to-nearest-even
__device__ __forceinline__ unsigned bfr(float x) {
    unsigned u = __float_as_uint(x);
    return (u + 0x7fffu + ((u >> 16) & 1u)) >> 16;
}
__device__ __forceinline__ uint4 pack8(float4 a, float4 b) {
    uint4 r;
    r.x = bfr(a.x) | (bfr(a.y) << 16);
    r.y = bfr(a.z) | (bfr(a.w) << 16);
    r.z = bfr(b.x) | (bfr(b.y) << 16);
    r.w = bfr(b.z) | (bfr(b.w) << 16);
    return r;
}

// unpack 8 bf16 from uint4 into 4 float2 pairs, packed-fma with splatted c2
#define BFMA2(acc, p, c2)                                                      \
    {                                                                          \
        f2 w;                                                                  \
        w.x = __uint_as_float((p).x << 16);                                    \
        w.y = __uint_as_float((p).x & 0xffff0000u);                            \
        acc[0] = __builtin_elementwise_fma(w, c2, acc[0]);                     \
        w.x = __uint_as_float((p).y << 16);                                    \
        w.y = __uint_as_float((p).y & 0xffff0000u);                            \
        acc[1] = __builtin_elementwise_fma(w, c2, acc[1]);                     \
        w.x = __uint_as_float((p).z << 16);                                    \
        w.y = __uint_as_float((p).z & 0xffff0000u);                            \
        acc[2] = __builtin_elementwise_fma(w, c2, acc[2]);                     \
        w.x = __uint_as_float((p).w << 16);                                    \
        w.y = __uint_as_float((p).w & 0xffff0000u);                            \
        acc[3] = __builtin_elementwise_fma(w, c2, acc[3]);                     \
    }

// cnt[t]++ per edge (atomic return = rank within bucket); threads <= N also
// build calT (transpose of calcium, row N zeroed).
__global__ void hist_kernel(const int* __restrict__ tgt, int* __restrict__ cnt,
                            int* __restrict__ rank, const float* __restrict__ cal,
                            float* __restrict__ calT, int N, int E) {
    int i = blockIdx.x * blockDim.x + threadIdx.x;
    if (i <= N) {
        float4* o = (float4*)(calT + (size_t)i * 8);
        if (i == N) {
            o[0] = make_float4(0.f, 0.f, 0.f, 0.f);
            o[1] = make_float4(0.f, 0.f, 0.f, 0.f);
        } else {
            float v[8];
#pragma unroll
            for (int b = 0; b < 8; ++b) v[b] = cal[(size_t)b * N + i];
            o[0] = make_float4(v[0], v[1], v[2], v[3]);
            o[1] = make_float4(v[4], v[5], v[6], v[7]);
        }
    }
    int base = i * 4;
    if (base + 3 < E) {
        int4 t = *(const int4*)(tgt + base);
        int4 r;
        r.x = atomicAdd(&cnt[t.x], 1);
        r.y = atomicAdd(&cnt[t.y], 1);
        r.z = atomicAdd(&cnt[t.z], 1);
        r.w = atomicAdd(&cnt[t.w], 1);
        *(int4*)(rank + base) = r;
    } else {
        for (int k = base; k < E; ++k) rank[k] = atomicAdd(&cnt[tgt[k]], 1);
    }
}

// Row allocation without a global scan: block-local exclusive scan of cnt,
// one atomicAdd(cursor, blockTotal) per block. Writes rowCnt = {begin, count}.
__global__ __launch_bounds__(256) void alloc_kernel(const int* __restrict__ cnt,
                                                    int2* __restrict__ rowCnt,
                                                    int* __restrict__ cursor, int N) {
    __shared__ int waveSum[4];
    const int n = blockIdx.x * 256 + threadIdx.x;
    const int lane = threadIdx.x & 63;
    const int wid = threadIdx.x >> 6;
    int c = (n < N) ? cnt[n] : 0;
    int pre = c;
#pragma unroll
    for (int off = 1; off < 64; off <<= 1) {
        int v = __shfl_up(pre, off, 64);
        if (lane >= off) pre += v;
    }
    if (lane == 63) waveSum[wid] = pre;
    __syncthreads();
    if (threadIdx.x == 0) {
        int s0 = waveSum[0], s1 = waveSum[1], s2 = waveSum[2], s3 = waveSum[3];
        int base = atomicAdd(cursor, s0 + s1 + s2 + s3);
        waveSum[0] = base;
        waveSum[1] = base + s0;
        waveSum[2] = base + s0 + s1;
        waveSum[3] = base + s0 + s1 + s2;
    }
    __syncthreads();
    if (n < N) rowCnt[n] = make_int2(waveSum[wid] + (pre - c), c);
}

// LANE-COOPERATIVE packer: 4 consecutive lanes own one edge. Lane q packs
// quarter q of the 64B record (q=0..2: W rows; q=3: calT[src]) and stores one
// uint4 at recs[pos*4+q]. Lanes 4k..4k+3 write consecutive 16B -> each record
// is a single fully-dirty 64B line per store instruction.
__global__ __launch_bounds__(256) void pack_store(
    const int* __restrict__ src, const int* __restrict__ tgt,
    const int* __restrict__ rank, const int2* __restrict__ rowCnt,
    const float* __restrict__ Wz, const float* __restrict__ Wr,
    const float* __restrict__ Wh, const float* __restrict__ calT,
    uint4* __restrict__ recs, int E) {
    int gid = blockIdx.x * 256 + threadIdx.x;
    int e = gid >> 2;
    int q = gid & 3;
    if (e >= E) return;
    int t = tgt[e];                        // broadcast across the 4 lanes
    int pos = rowCnt[t].x + rank[e];
    const float* base;
    size_t off;
    if (q == 0)      { base = Wz;   off = (size_t)e * 8; }
    else if (q == 1) { base = Wr;   off = (size_t)e * 8; }
    else if (q == 2) { base = Wh;   off = (size_t)e * 8; }
    else             { base = calT; off = (size_t)src[e] * 8; }
    const float4* p = (const float4*)(base + off);
    float4 a = p[0], b = p[1];
    recs[(size_t)pos * 4 + q] = pack8(a, b);
}

// xor reduce-scatter over the 8 s-lanes: input v[0..7] partials per lane,
// output = fully-reduced value for element index s (lane bits 3,4,5).
__device__ __forceinline__ float rscatter(float v[8], int lane) {
    const bool s0 = (lane & 8) != 0;
    const bool s1 = (lane & 16) != 0;
    const bool s2 = (lane & 32) != 0;
    float w0, w1, w2, w3, x0, x1;
    { float k = s0 ? v[1] : v[0], g = s0 ? v[0] : v[1]; w0 = k + __shfl_xor(g, 8, 64); }
    { float k = s0 ? v[3] : v[2], g = s0 ? v[2] : v[3]; w1 = k + __shfl_xor(g, 8, 64); }
    { float k = s0 ? v[5] : v[4], g = s0 ? v[4] : v[5]; w2 = k + __shfl_xor(g, 8, 64); }
    { float k = s0 ? v[7] : v[6], g = s0 ? v[6] : v[7]; w3 = k + __shfl_xor(g, 8, 64); }
    { float k = s1 ? w1 : w0, g = s1 ? w0 : w1; x0 = k + __shfl_xor(g, 16, 64); }
    { float k = s1 ? w3 : w2, g = s1 ? w2 : w3; x1 = k + __shfl_xor(g, 16, 64); }
    float k = s2 ? x1 : x0, g = s2 ? x0 : x1;
    return k + __shfl_xor(g, 32, 64);
}

// Main: one wave per neuron, 256-thread blocks (4 neurons). lane = s*8 + b.
// Sparse loop streams self-contained 64B records; all math packed f32x2.
// Identical to R14 (control: absmax must stay exactly 0.03125).
__global__ __launch_bounds__(256) void gru_main(
    const float* __restrict__ hidden, const uint4* __restrict__ recs,
    const float* __restrict__ Uz, const float* __restrict__ Ur,
    const float* __restrict__ Uh, const float* __restrict__ bz,
    const float* __restrict__ br, const float* __restrict__ bh,
    const float* __restrict__ proj, const int2* __restrict__ rowCnt,
    float* __restrict__ outCal, float* __restrict__ outHid, int N) {
    const int lane = threadIdx.x & 63;
    const int n = blockIdx.x * 4 + (threadIdx.x >> 6);
    if (n >= N) return;
    const int s = lane >> 3;  // slot / h-element index
    const int b = lane & 7;   // batch

    const int2 rc = rowCnt[n];
    const int start = rc.x;
    const int end = rc.x + rc.y;

    // ---- hoisted dense-phase loads (latency hides under the sparse loop) ----
    const float hvS = hidden[((b * N + n) << 3) + s];
    const int ub = (n << 6) + (s << 3);
    const f2* uz2 = (const f2*)(Uz + ub);
    const f2* ur2 = (const f2*)(Ur + ub);
    const f2* uh2 = (const f2*)(Uh + ub);
    f2 uzr[4], urr[4], uhr[4];
#pragma unroll
    for (int k = 0; k < 4; ++k) {
        uzr[k] = uz2[k];
        urr[k] = ur2[k];
        uhr[k] = uh2[k];
    }
    const float bzS = bz[(n << 3) + s];
    const float brS = br[(n << 3) + s];
    const float bhS = bh[(n << 3) + s];
    const float pjS = proj[s];

    f2 az2[4], ar2[4], ah2[4];
#pragma unroll
    for (int k = 0; k < 4; ++k) {
        az2[k] = (f2){0.0f, 0.0f};
        ar2[k] = (f2){0.0f, 0.0f};
        ah2[k] = (f2){0.0f, 0.0f};
    }

    // ---- sparse phase: lane s streams records j = start+s, +8, ... ----
    const unsigned short* recsH = (const unsigned short*)recs;
    for (int j = start + s; j < end; j += 8) {
        const uint4* rp = recs + (size_t)j * 4;
        uint4 pz = rp[0];
        uint4 pr = rp[1];
        uint4 ph = rp[2];
        unsigned cb = recsH[((size_t)j << 5) + 24 + b];
        float c = __uint_as_float(cb << 16);
        f2 c2 = {c, c};
        BFMA2(az2, pz, c2);
        BFMA2(ar2, pr, c2);
        BFMA2(ah2, ph, c2);
    }

    // ---- slot-parallel recurrent partials for h = s (packed) ----
    f2 hv2 = {hvS, hvS};
#pragma unroll
    for (int k = 0; k < 4; ++k) {
        az2[k] = __builtin_elementwise_fma(uzr[k], hv2, az2[k]);
        ar2[k] = __builtin_elementwise_fma(urr[k], hv2, ar2[k]);
    }

    // ---- reduce-scatter -> element-s scalars ----
    float az[8], ar[8];
#pragma unroll
    for (int k = 0; k < 4; ++k) {
        az[2 * k] = az2[k].x; az[2 * k + 1] = az2[k].y;
        ar[2 * k] = ar2[k].x; ar[2 * k + 1] = ar2[k].y;
    }
    float AZ = rscatter(az, lane);
    float AR = rscatter(ar, lane);
    float z = fast_sigmoid(AZ + bzS);
    float r = fast_sigmoid(AR + brS);
    float rhS = r * hvS;

    f2 rh2 = {rhS, rhS};
#pragma unroll
    for (int k = 0; k < 4; ++k) {
        ah2[k] = __builtin_elementwise_fma(uhr[k], rh2, ah2[k]);
    }
    float ah[8];
#pragma unroll
    for (int k = 0; k < 4; ++k) {
        ah[2 * k] = ah2[k].x; ah[2 * k + 1] = ah2[k].y;
    }
    float AH = rscatter(ah, lane);
    float ht = fast_tanh(AH + bhS);
    float hn = (1.0f - z) * hvS + z * ht;

    // ---- projection: butterfly all-reduce over s ----
    float cv = hn * pjS;
    cv += __shfl_xor(cv, 8, 64);
    cv += __shfl_xor(cv, 16, 64);
    cv += __shfl_xor(cv, 32, 64);

    outHid[((b * N + n) << 3) + s] = hn;
    if (s == 0) outCal[b * N + n] = fmaxf(cv, 0.0f);
}

extern "C" void kernel_launch(void* const* d_in, const int* in_sizes, int n_in,
                              void* d_out, int out_size, void* d_ws, size_t ws_size,
                              hipStream_t stream) {
    const float* calcium = (const float*)d_in[0];
    const float* hidden  = (const float*)d_in[1];
    const int*   src     = (const int*)d_in[2];
    const int*   tgt     = (const int*)d_in[3];
    const float* Wz      = (const float*)d_in[4];
    const float* Wr      = (const float*)d_in[5];
    const float* Wh      = (const float*)d_in[6];
    const float* Uz      = (const float*)d_in[7];
    const float* Ur      = (const float*)d_in[8];
    const float* Uh      = (const float*)d_in[9];
    const float* bz      = (const float*)d_in[10];
    const float* br      = (const float*)d_in[11];
    const float* bh      = (const float*)d_in[12];
    const float* proj    = (const float*)d_in[13];

    const int E = in_sizes[2];
    const int H = in_sizes[13];           // 8
    const int N = in_sizes[10] / H;       // 70000
    (void)n_in; (void)out_size; (void)ws_size;

    float* out = (float*)d_out;
    float* outCal = out;
    float* outHid = out + (size_t)in_sizes[0];

    char* ws = (char*)d_ws;
    int*   cnt    = (int*)ws;
    int*   cursor = (int*)(ws + (448 << 10));
    int2*  rowCnt = (int2*)(ws + (512 << 10));
    int*   rank   = (int*)(ws + (1280 << 10));
    float* calT   = (float*)(ws + (5888 << 10));
    uint4* recs   = (uint4*)(ws + (8320 << 10));

    // zero cnt [0,280K) and cursor (at 448K) in one memset
    hipMemsetAsync(ws, 0, (448 << 10) + 4, stream);

    int histThreads = (E + 3) / 4;  // 280000 >= N+1, covers calT duty too
    hist_kernel<<<(histThreads + 255) / 256, 256, 0, stream>>>(
        tgt, cnt, rank, calcium, calT, N, E);
    alloc_kernel<<<(N + 255) / 256, 256, 0, stream>>>(cnt, rowCnt, cursor, N);
    {
        long long pthreads = (long long)E * 4;
        pack_store<<<(int)((pthreads + 255) / 256), 256, 0, stream>>>(
            src, tgt, rank, rowCnt, Wz, Wr, Wh, calT, recs, E);
    }
    gru_main<<<(N + 3) / 4, 256, 0, stream>>>(
        hidden, recs, Uz, Ur, Uh, bz, br, bh, proj,
        rowCnt, outCal, outHid, N);
}